// Round 1
// baseline (1468.827 us; speedup 1.0000x reference)
//
#include <hip/hip_runtime.h>
#include <math.h>

// Problem constants (from reference): D=256, E=1024, F=1024, N=4096.
// out[n,f] = sum_d x[n,d] * W_eff[d,f] + b_eff[f]
//   W_eff[d,f] = sum_e w[e,f] * expert_W[e,d,f]   (w = softmax(x[:1024] @ gate_W + gate_b))
//   b_eff[f]   = sum_e w[e,f] * expert_b[e,f]
//
// ws layout (floats):
//   [0, 1048576)            : w      (1024 x 1024)
//   [1048576, 1048576+257K) : weff   (257 x 1024); rows 0..255 = W_eff, row 256 = b_eff
// total ~5.03 MB of d_ws used.

#define DD 256
#define EE 1024
#define FF 1024
#define NN 4096

// ---------------- Kernel A: gate GEMM + row softmax (rows 0..1023 only) ----------------
// grid 256 blocks x 256 threads; each block does 4 rows x 1024 cols.
__global__ __launch_bounds__(256) void gate_kernel(const float* __restrict__ x,
                                                   const float* __restrict__ gW,
                                                   const float* __restrict__ gb,
                                                   float* __restrict__ w_out) {
    __shared__ float xs[4 * DD];       // 4 KB
    __shared__ float ls[4 * EE];       // 16 KB logits
    const int tid = threadIdx.x;
    const int r0 = blockIdx.x * 4;

    // load 4 rows of x (1024 floats) -> one float4 per thread
    ((float4*)xs)[tid] = ((const float4*)(x + (size_t)r0 * DD))[tid];
    __syncthreads();

    float4 a0 = {0,0,0,0}, a1 = {0,0,0,0}, a2 = {0,0,0,0}, a3 = {0,0,0,0};
    const float4* gw4 = (const float4*)gW;   // row d: d*256 float4s; this thread's cols = float4 #tid
    #pragma unroll 4
    for (int d = 0; d < DD; ++d) {
        float4 g = gw4[d * 256 + tid];
        float x0 = xs[0*DD + d], x1 = xs[1*DD + d], x2 = xs[2*DD + d], x3 = xs[3*DD + d];
        a0.x += x0*g.x; a0.y += x0*g.y; a0.z += x0*g.z; a0.w += x0*g.w;
        a1.x += x1*g.x; a1.y += x1*g.y; a1.z += x1*g.z; a1.w += x1*g.w;
        a2.x += x2*g.x; a2.y += x2*g.y; a2.z += x2*g.z; a2.w += x2*g.w;
        a3.x += x3*g.x; a3.y += x3*g.y; a3.z += x3*g.z; a3.w += x3*g.w;
    }
    float4 b = ((const float4*)gb)[tid];
    a0.x += b.x; a0.y += b.y; a0.z += b.z; a0.w += b.w;
    a1.x += b.x; a1.y += b.y; a1.z += b.z; a1.w += b.w;
    a2.x += b.x; a2.y += b.y; a2.z += b.z; a2.w += b.w;
    a3.x += b.x; a3.y += b.y; a3.z += b.z; a3.w += b.w;
    ((float4*)&ls[0*EE])[tid] = a0;
    ((float4*)&ls[1*EE])[tid] = a1;
    ((float4*)&ls[2*EE])[tid] = a2;
    ((float4*)&ls[3*EE])[tid] = a3;
    __syncthreads();

    // softmax: one wave (64 lanes) per row; 16 values per lane, stride 64
    const int lane = tid & 63;
    const int row = tid >> 6;    // 0..3
    float vals[16];
    float m = -3.0e38f;
    #pragma unroll
    for (int i = 0; i < 16; ++i) {
        vals[i] = ls[row * EE + i * 64 + lane];
        m = fmaxf(m, vals[i]);
    }
    #pragma unroll
    for (int off = 1; off < 64; off <<= 1) m = fmaxf(m, __shfl_xor(m, off));
    float s = 0.0f;
    #pragma unroll
    for (int i = 0; i < 16; ++i) {
        vals[i] = __expf(vals[i] - m);
        s += vals[i];
    }
    #pragma unroll
    for (int off = 1; off < 64; off <<= 1) s += __shfl_xor(s, off);
    const float inv = 1.0f / s;
    float* wrow = w_out + (size_t)(r0 + row) * EE;
    #pragma unroll
    for (int i = 0; i < 16; ++i) wrow[i * 64 + lane] = vals[i] * inv;
}

// ---------------- Kernel B: W_eff / b_eff reduction (HBM-bound streaming) ----------------
// grid 1028 blocks x 256 threads. block = (slice, chunk): slice 0..255 -> expert_W d-slice,
// slice 256 -> expert_b; chunk 0..3 -> e in [chunk*256, chunk*256+256).
__global__ __launch_bounds__(256) void weff_kernel(const float* __restrict__ eW,
                                                   const float* __restrict__ eb,
                                                   const float* __restrict__ w,
                                                   float* __restrict__ weff) {
    const int tid = threadIdx.x;
    const int slice = blockIdx.x >> 2;     // 0..256
    const int chunk = blockIdx.x & 3;
    const int f = tid * 4;

    const float* p;
    size_t estride;
    if (slice < DD) {
        p = eW + (size_t)slice * FF + f;
        estride = (size_t)DD * FF;         // 262144
    } else {
        p = eb + f;
        estride = FF;                      // 1024
    }
    const int e0 = chunk * 256;
    p += (size_t)e0 * estride;
    const float* q = w + (size_t)e0 * EE + f;

    float4 acc = {0,0,0,0};
    #pragma unroll 4
    for (int i = 0; i < 256; ++i) {
        float4 a = *(const float4*)p;
        float4 ww = *(const float4*)q;
        acc.x += a.x * ww.x;
        acc.y += a.y * ww.y;
        acc.z += a.z * ww.z;
        acc.w += a.w * ww.w;
        p += estride;
        q += EE;
    }
    float* dst = weff + (size_t)slice * FF + f;
    atomicAdd(dst + 0, acc.x);
    atomicAdd(dst + 1, acc.y);
    atomicAdd(dst + 2, acc.z);
    atomicAdd(dst + 3, acc.w);
}

// ---------------- Kernel C: out = x @ W_eff + b_eff ----------------
// grid 256 blocks x 256 threads; block = 16 rows x 1024 cols; thread = 16 rows x float4 cols.
__global__ __launch_bounds__(256) void out_kernel(const float* __restrict__ x,
                                                  const float* __restrict__ weff,
                                                  float* __restrict__ out) {
    __shared__ float xs[16 * DD];   // 16 KB
    const int tid = threadIdx.x;
    const int n0 = blockIdx.x * 16;

    // load 16x256 x-tile = 1024 float4, 4 per thread
    {
        const float4* xsrc = (const float4*)(x + (size_t)n0 * DD);
        float4* xd = (float4*)xs;
        #pragma unroll
        for (int k = 0; k < 4; ++k) xd[tid + k * 256] = xsrc[tid + k * 256];
    }
    __syncthreads();

    float4 acc[16];
    #pragma unroll
    for (int r = 0; r < 16; ++r) acc[r] = make_float4(0.f, 0.f, 0.f, 0.f);

    const float4* wp = (const float4*)weff + tid;   // row d at d*256 float4s
    #pragma unroll 2
    for (int d = 0; d < DD; ++d) {
        float4 g = wp[d * 256];
        #pragma unroll
        for (int r = 0; r < 16; ++r) {
            float xv = xs[r * DD + d];   // LDS broadcast (same addr across lanes)
            acc[r].x += xv * g.x;
            acc[r].y += xv * g.y;
            acc[r].z += xv * g.z;
            acc[r].w += xv * g.w;
        }
    }

    float4 b = ((const float4*)(weff + (size_t)DD * FF))[tid];   // b_eff row
    #pragma unroll
    for (int r = 0; r < 16; ++r) {
        float4 o;
        o.x = acc[r].x + b.x;
        o.y = acc[r].y + b.y;
        o.z = acc[r].z + b.z;
        o.w = acc[r].w + b.w;
        ((float4*)(out + (size_t)(n0 + r) * FF))[tid] = o;
    }
}

extern "C" void kernel_launch(void* const* d_in, const int* in_sizes, int n_in,
                              void* d_out, int out_size, void* d_ws, size_t ws_size,
                              hipStream_t stream) {
    const float* x  = (const float*)d_in[0];
    const float* gW = (const float*)d_in[1];
    const float* gb = (const float*)d_in[2];
    const float* eW = (const float*)d_in[3];
    const float* eb = (const float*)d_in[4];
    float* out = (float*)d_out;

    float* ws   = (float*)d_ws;
    float* w    = ws;                       // 1024*1024 floats
    float* weff = ws + (size_t)EE * EE;     // 257*1024 floats

    // weff is accumulated with atomics -> must be zeroed every call (ws is re-poisoned)
    hipMemsetAsync(weff, 0, (size_t)(DD + 1) * FF * sizeof(float), stream);

    gate_kernel<<<dim3(256), dim3(256), 0, stream>>>(x, gW, gb, w);
    weff_kernel<<<dim3(1028), dim3(256), 0, stream>>>(eW, eb, w, weff);
    out_kernel<<<dim3(256), dim3(256), 0, stream>>>(x, weff, out);
}